// Round 1
// baseline (419.571 us; speedup 1.0000x reference)
//
#include <hip/hip_runtime.h>

typedef __bf16 bf16;
typedef __bf16 bf16x8 __attribute__((ext_vector_type(8)));
typedef float f32x4 __attribute__((ext_vector_type(4)));

#define GLDS16(gp, lp) __builtin_amdgcn_global_load_lds( \
    (__attribute__((address_space(1))) void*)(gp), \
    (__attribute__((address_space(3))) void*)(lp), 16, 0, 0)

// ---------------- conversion kernels ----------------

__global__ void f2b_kernel(const float* __restrict__ src, bf16* __restrict__ dst, long n) {
    long i = ((long)blockIdx.x * 256 + threadIdx.x) * 4;
    if (i + 3 < n) {
        float4 v = *(const float4*)&src[i];
        dst[i + 0] = (bf16)v.x;
        dst[i + 1] = (bf16)v.y;
        dst[i + 2] = (bf16)v.z;
        dst[i + 3] = (bf16)v.w;
    }
}

// W: K x N (f32, row-major) -> WT: N x K (bf16, row-major)
__global__ __launch_bounds__(256) void transpose_f2b(const float* __restrict__ W,
                                                     bf16* __restrict__ WT,
                                                     int K, int N) {
    __shared__ float tile[32][33];
    int tx = threadIdx.x & 31;
    int ty = threadIdx.x >> 5;               // 0..7
    int n0 = blockIdx.x * 32;
    int k0 = blockIdx.y * 32;
#pragma unroll
    for (int i = 0; i < 4; ++i)
        tile[ty + i * 8][tx] = W[(long)(k0 + ty + i * 8) * N + n0 + tx];
    __syncthreads();
#pragma unroll
    for (int i = 0; i < 4; ++i)
        WT[(long)(n0 + ty + i * 8) * K + k0 + tx] = (bf16)tile[tx][ty + i * 8];
}

// ---------------- GEMM (m97-style 128x128, BK=32) ----------------
// C[M,N] = A[M,K] * BT[N,K]^T + bias ; A,BT bf16 row-major, acc f32.
template <bool OUT_F32>
__global__ __launch_bounds__(256) void gemm_bt(const bf16* __restrict__ A,
                                               const bf16* __restrict__ BT,
                                               const float* __restrict__ bias,
                                               void* __restrict__ C,
                                               int M, int N, int K) {
    __shared__ bf16 Asm[128 * 32];
    __shared__ bf16 Bsm[128 * 32];
    int tid = threadIdx.x;
    int w = tid >> 6, l = tid & 63;
    int wr = w >> 1, wc = w & 1;
    int bm = blockIdx.x * 128;
    int bn = blockIdx.y * 128;

    f32x4 acc[4][4] = {};

    int arow = l >> 2;            // 0..15 within chunk
    int acol = (l & 3) * 8;       // 0,8,16,24
    int fr = l & 15;
    int fk = (l >> 4) * 8;        // 0,8,16,24

    int nk = K >> 5;
    for (int kt = 0; kt < nk; ++kt) {
        int k0 = kt * 32;
#pragma unroll
        for (int it = 0; it < 2; ++it) {
            int c = it * 4 + w;   // chunk 0..7, wave-uniform
            const bf16* ga = A + (long)(bm + c * 16 + arow) * K + k0 + acol;
            GLDS16(ga, &Asm[c * 512]);
            const bf16* gb = BT + (long)(bn + c * 16 + arow) * K + k0 + acol;
            GLDS16(gb, &Bsm[c * 512]);
        }
        asm volatile("s_waitcnt vmcnt(0)" ::: "memory");
        __syncthreads();

        bf16x8 af[4], bfr[4];
#pragma unroll
        for (int m = 0; m < 4; ++m)
            af[m] = *(const bf16x8*)&Asm[(wr * 64 + m * 16 + fr) * 32 + fk];
#pragma unroll
        for (int n = 0; n < 4; ++n)
            bfr[n] = *(const bf16x8*)&Bsm[(wc * 64 + n * 16 + fr) * 32 + fk];
#pragma unroll
        for (int m = 0; m < 4; ++m)
#pragma unroll
            for (int n = 0; n < 4; ++n)
                acc[m][n] = __builtin_amdgcn_mfma_f32_16x16x32_bf16(af[m], bfr[n], acc[m][n], 0, 0, 0);
        __syncthreads();
    }

    int orow0 = bm + wr * 64;
    int ocol0 = bn + wc * 64;
#pragma unroll
    for (int m = 0; m < 4; ++m) {
        int row = orow0 + m * 16 + (l >> 4) * 4;
#pragma unroll
        for (int n = 0; n < 4; ++n) {
            int col = ocol0 + n * 16 + (l & 15);
            float bv = bias[col];
#pragma unroll
            for (int r = 0; r < 4; ++r) {
                float v = acc[m][n][r] + bv;
                if (OUT_F32)
                    ((float*)C)[(long)(row + r) * N + col] = v;
                else
                    ((bf16*)C)[(long)(row + r) * N + col] = (bf16)v;
            }
        }
    }
}

// ---------------- QKV: rmsnorm + rope + v-transpose ----------------
// h: [4096, 7168] bf16. q,k out: [(b*16+hh), 2048, 64]; vT out: [(b*16+hh), 64, 2048]
__global__ __launch_bounds__(64) void qkv_kernel(const bf16* __restrict__ h,
                                                 const float* __restrict__ pe,
                                                 const float* __restrict__ qsc_,
                                                 const float* __restrict__ ksc_,
                                                 bf16* __restrict__ qo,
                                                 bf16* __restrict__ ko,
                                                 bf16* __restrict__ vTo) {
    int t = blockIdx.x;
    int b = t >> 11;
    int lpos = t & 2047;
    int d = threadIdx.x;
    const bf16* hrow = h + (long)t * 7168;
    // pe flat: (2048, 32, 2, 2): idx = lpos*128 + dd*4 + j*2 + i ; d = 2*dd + j
    float pe0 = pe[lpos * 128 + (d >> 1) * 4 + (d & 1) * 2 + 0];
    float pe1 = pe[lpos * 128 + (d >> 1) * 4 + (d & 1) * 2 + 1];
    float qsc = qsc_[d], ksc = ksc_[d];
#pragma unroll 1
    for (int hh = 0; hh < 16; ++hh) {
        float qv = (float)hrow[hh * 64 + d];
        float kv = (float)hrow[1024 + hh * 64 + d];
        float ssq = qv * qv, ssk = kv * kv;
#pragma unroll
        for (int off = 1; off < 64; off <<= 1) {
            ssq += __shfl_xor(ssq, off, 64);
            ssk += __shfl_xor(ssk, off, 64);
        }
        float qn = qv * rsqrtf(ssq * (1.0f / 64.0f) + 1e-6f) * qsc;
        float kn = kv * rsqrtf(ssk * (1.0f / 64.0f) + 1e-6f) * ksc;
        float qe = __shfl(qn, d & 62, 64), qodd = __shfl(qn, d | 1, 64);
        float ke = __shfl(kn, d & 62, 64), kodd = __shfl(kn, d | 1, 64);
        float qr = pe0 * qe + pe1 * qodd;
        float kr = pe0 * ke + pe1 * kodd;
        long base = ((long)(b * 16 + hh) * 2048 + lpos) * 64 + d;
        qo[base] = (bf16)qr;
        ko[base] = (bf16)kr;
        vTo[((long)(b * 16 + hh) * 64 + d) * 2048 + lpos] = hrow[2048 + hh * 64 + d];
    }
}

// ---------------- GELU (tanh approx, matches jax.nn.gelu default) ----------------
__global__ void gelu_kernel(const bf16* __restrict__ h, bf16* __restrict__ cat) {
    long e = ((long)blockIdx.x * 256 + threadIdx.x) * 8;
    int t = (int)(e >> 12);
    int j = (int)(e & 4095);
    bf16x8 v = *(const bf16x8*)&h[(long)t * 7168 + 3072 + j];
    bf16x8 o;
#pragma unroll
    for (int r = 0; r < 8; ++r) {
        float x = (float)v[r];
        float g = 0.5f * x * (1.0f + tanhf(0.7978845608028654f * (x + 0.044715f * x * x * x)));
        o[r] = (bf16)g;
    }
    *(bf16x8*)&cat[(long)t * 5120 + 1024 + j] = o;
}

// ---------------- Flash attention ----------------
// grid: bh*32 + qtile. 4 waves; each wave owns 16 q-rows. KV tile = 64.
__global__ __launch_bounds__(256) void attn_kernel(const bf16* __restrict__ q,
                                                   const bf16* __restrict__ k,
                                                   const bf16* __restrict__ vT,
                                                   bf16* __restrict__ cat) {
    __shared__ bf16 Ksm[64 * 72];      // [kv][d] padded
    __shared__ bf16 Vsm[64 * 72];      // [d][kv] padded (V^T)
    __shared__ bf16 Psm[4][16 * 72];   // per-wave P [qrow][kv] padded

    int bidx = blockIdx.x;
    int bh = bidx >> 5;
    int qt = bidx & 31;
    int b = bh >> 4, hh = bh & 15;
    int q0 = qt * 64;
    int tid = threadIdx.x, w = tid >> 6, l = tid & 63;
    int fr = l & 15;
    int fk8 = (l >> 4) * 8;

    // Q fragments (held in regs whole kernel)
    const bf16* qbase = q + ((long)bh * 2048 + q0 + w * 16 + fr) * 64;
    bf16x8 qf0 = *(const bf16x8*)&qbase[fk8];
    bf16x8 qf1 = *(const bf16x8*)&qbase[32 + fk8];

    f32x4 Of[4] = {};
    float mrow[4], lrow[4];
#pragma unroll
    for (int r = 0; r < 4; ++r) { mrow[r] = -1e30f; lrow[r] = 0.0f; }

    for (int kv0 = 0; kv0 < 2048; kv0 += 64) {
        __syncthreads();
        // stage K [64][64] and V^T [64][64] into padded LDS
#pragma unroll
        for (int it = 0; it < 2; ++it) {
            int seg = tid + it * 256;
            int row = seg >> 3, cb = (seg & 7) * 8;
            *(bf16x8*)&Ksm[row * 72 + cb] =
                *(const bf16x8*)&k[((long)bh * 2048 + kv0 + row) * 64 + cb];
            *(bf16x8*)&Vsm[row * 72 + cb] =
                *(const bf16x8*)&vT[((long)bh * 64 + row) * 2048 + kv0 + cb];
        }
        __syncthreads();

        // scores S = Q K^T * 0.125
        f32x4 S[4];
#pragma unroll
        for (int n = 0; n < 4; ++n) {
            f32x4 z = {};
            bf16x8 kb0 = *(const bf16x8*)&Ksm[(n * 16 + fr) * 72 + fk8];
            bf16x8 kb1 = *(const bf16x8*)&Ksm[(n * 16 + fr) * 72 + 32 + fk8];
            z = __builtin_amdgcn_mfma_f32_16x16x32_bf16(qf0, kb0, z, 0, 0, 0);
            z = __builtin_amdgcn_mfma_f32_16x16x32_bf16(qf1, kb1, z, 0, 0, 0);
            S[n] = z;
        }

        // online softmax (rows live in 16-lane groups; row = (l>>4)*4 + r)
#pragma unroll
        for (int r = 0; r < 4; ++r) {
            float s0 = S[0][r] * 0.125f, s1 = S[1][r] * 0.125f;
            float s2 = S[2][r] * 0.125f, s3 = S[3][r] * 0.125f;
            float mx = fmaxf(fmaxf(s0, s1), fmaxf(s2, s3));
#pragma unroll
            for (int off = 1; off < 16; off <<= 1) mx = fmaxf(mx, __shfl_xor(mx, off, 64));
            float mnew = fmaxf(mrow[r], mx);
            float scale = expf(mrow[r] - mnew);
            float p0 = expf(s0 - mnew), p1 = expf(s1 - mnew);
            float p2 = expf(s2 - mnew), p3 = expf(s3 - mnew);
            float rs = p0 + p1 + p2 + p3;
#pragma unroll
            for (int off = 1; off < 16; off <<= 1) rs += __shfl_xor(rs, off, 64);
            lrow[r] = lrow[r] * scale + rs;
            mrow[r] = mnew;
#pragma unroll
            for (int j = 0; j < 4; ++j) Of[j][r] *= scale;
            int prow = (l >> 4) * 4 + r;
            Psm[w][prow * 72 + 0 * 16 + fr] = (bf16)p0;
            Psm[w][prow * 72 + 1 * 16 + fr] = (bf16)p1;
            Psm[w][prow * 72 + 2 * 16 + fr] = (bf16)p2;
            Psm[w][prow * 72 + 3 * 16 + fr] = (bf16)p3;
        }

        // PV: Of += P(16xkv) V(kv x 64)
#pragma unroll
        for (int ks = 0; ks < 2; ++ks) {
            bf16x8 pa = *(const bf16x8*)&Psm[w][fr * 72 + ks * 32 + fk8];
#pragma unroll
            for (int j = 0; j < 4; ++j) {
                bf16x8 vb = *(const bf16x8*)&Vsm[(j * 16 + fr) * 72 + ks * 32 + fk8];
                Of[j] = __builtin_amdgcn_mfma_f32_16x16x32_bf16(pa, vb, Of[j], 0, 0, 0);
            }
        }
    }

    // epilogue: normalize, write into concat[:, hh*64 + ...]
    int rowl = (l >> 4) * 4;
#pragma unroll
    for (int j = 0; j < 4; ++j) {
        int col = hh * 64 + j * 16 + fr;
#pragma unroll
        for (int r = 0; r < 4; ++r) {
            float v = Of[j][r] / lrow[r];
            int trow = b * 2048 + q0 + w * 16 + rowl + r;
            cat[(long)trow * 5120 + col] = (bf16)v;
        }
    }
}

// ---------------- launch ----------------

extern "C" void kernel_launch(void* const* d_in, const int* in_sizes, int n_in,
                              void* d_out, int out_size, void* d_ws, size_t ws_size,
                              hipStream_t stream) {
    const float* x  = (const float*)d_in[0];
    const float* pe = (const float*)d_in[1];
    const float* W1 = (const float*)d_in[2];
    const float* b1 = (const float*)d_in[3];
    const float* W2 = (const float*)d_in[4];
    const float* b2 = (const float*)d_in[5];
    const float* qs = (const float*)d_in[6];
    const float* ks = (const float*)d_in[7];
    float* out = (float*)d_out;

    char* ws = (char*)d_ws;
    bf16* xb  = (bf16*)(ws);                  // 4096*1024*2      =  8388608
    bf16* w1t = (bf16*)(ws + 8388608);        // 7168*1024*2      = 14680064
    bf16* w2t = (bf16*)(ws + 23068672);       // 1024*5120*2      = 10485760
    bf16* h   = (bf16*)(ws + 33554432);       // 4096*7168*2      = 58720256
    bf16* qb  = (bf16*)(ws + 92274688);       // 32*2048*64*2     =  8388608
    bf16* kb  = (bf16*)(ws + 100663296);      //                  =  8388608
    bf16* vT  = (bf16*)(ws + 109051904);      //                  =  8388608
    bf16* cat = (bf16*)(ws + 117440512);      // 4096*5120*2      = 41943040
    // total 159383552 bytes

    f2b_kernel<<<4096, 256, 0, stream>>>(x, xb, 4194304L);
    transpose_f2b<<<dim3(224, 32), 256, 0, stream>>>(W1, w1t, 1024, 7168);
    transpose_f2b<<<dim3(32, 160), 256, 0, stream>>>(W2, w2t, 5120, 1024);

    gemm_bt<false><<<dim3(32, 56), 256, 0, stream>>>(xb, w1t, b1, h, 4096, 7168, 1024);

    qkv_kernel<<<4096, 64, 0, stream>>>(h, pe, qs, ks, qb, kb, vT);
    gelu_kernel<<<8192, 256, 0, stream>>>(h, cat);

    attn_kernel<<<1024, 256, 0, stream>>>(qb, kb, vT, cat);

    gemm_bt<true><<<dim3(32, 8), 256, 0, stream>>>(cat, w2t, b2, out, 4096, 1024, 5120);
}

// Round 3
// 334.340 us; speedup vs baseline: 1.2549x; 1.2549x over previous
//
#include <hip/hip_runtime.h>

typedef __bf16 bf16;
typedef __bf16 bf16x8 __attribute__((ext_vector_type(8)));
typedef float f32x4 __attribute__((ext_vector_type(4)));
typedef float f32x16 __attribute__((ext_vector_type(16)));

#define GLDS16(gp, lp) __builtin_amdgcn_global_load_lds( \
    (__attribute__((address_space(1))) void*)(gp), \
    (__attribute__((address_space(3))) void*)(lp), 16, 0, 0)

__device__ inline float ex2(float x) { return exp2f(x); }

// ---------------- conversion kernels ----------------

__global__ void f2b_kernel(const float* __restrict__ src, bf16* __restrict__ dst, long n) {
    long i = ((long)blockIdx.x * 256 + threadIdx.x) * 4;
    if (i + 3 < n) {
        float4 v = *(const float4*)&src[i];
        dst[i + 0] = (bf16)v.x;
        dst[i + 1] = (bf16)v.y;
        dst[i + 2] = (bf16)v.z;
        dst[i + 3] = (bf16)v.w;
    }
}

// W: K x N (f32, row-major) -> WT: N x K (bf16, row-major)
__global__ __launch_bounds__(256) void transpose_f2b(const float* __restrict__ W,
                                                     bf16* __restrict__ WT,
                                                     int K, int N) {
    __shared__ float tile[32][33];
    int tx = threadIdx.x & 31;
    int ty = threadIdx.x >> 5;               // 0..7
    int n0 = blockIdx.x * 32;
    int k0 = blockIdx.y * 32;
#pragma unroll
    for (int i = 0; i < 4; ++i)
        tile[ty + i * 8][tx] = W[(long)(k0 + ty + i * 8) * N + n0 + tx];
    __syncthreads();
#pragma unroll
    for (int i = 0; i < 4; ++i)
        WT[(long)(n0 + ty + i * 8) * K + k0 + tx] = (bf16)tile[tx][ty + i * 8];
}

// ---------------- GEMM (m97-style 128x128, BK=32) ----------------
template <bool OUT_F32>
__global__ __launch_bounds__(256) void gemm_bt(const bf16* __restrict__ A,
                                               const bf16* __restrict__ BT,
                                               const float* __restrict__ bias,
                                               void* __restrict__ C,
                                               int M, int N, int K) {
    __shared__ bf16 Asm[128 * 32];
    __shared__ bf16 Bsm[128 * 32];
    int tid = threadIdx.x;
    int w = tid >> 6, l = tid & 63;
    int wr = w >> 1, wc = w & 1;
    int bm = blockIdx.x * 128;
    int bn = blockIdx.y * 128;

    f32x4 acc[4][4] = {};

    int arow = l >> 2;
    int acol = (l & 3) * 8;
    int fr = l & 15;
    int fk = (l >> 4) * 8;

    int nk = K >> 5;
    for (int kt = 0; kt < nk; ++kt) {
        int k0 = kt * 32;
#pragma unroll
        for (int it = 0; it < 2; ++it) {
            int c = it * 4 + w;
            const bf16* ga = A + (long)(bm + c * 16 + arow) * K + k0 + acol;
            GLDS16(ga, &Asm[c * 512]);
            const bf16* gb = BT + (long)(bn + c * 16 + arow) * K + k0 + acol;
            GLDS16(gb, &Bsm[c * 512]);
        }
        asm volatile("s_waitcnt vmcnt(0)" ::: "memory");
        __syncthreads();

        bf16x8 af[4], bfr[4];
#pragma unroll
        for (int m = 0; m < 4; ++m)
            af[m] = *(const bf16x8*)&Asm[(wr * 64 + m * 16 + fr) * 32 + fk];
#pragma unroll
        for (int n = 0; n < 4; ++n)
            bfr[n] = *(const bf16x8*)&Bsm[(wc * 64 + n * 16 + fr) * 32 + fk];
#pragma unroll
        for (int m = 0; m < 4; ++m)
#pragma unroll
            for (int n = 0; n < 4; ++n)
                acc[m][n] = __builtin_amdgcn_mfma_f32_16x16x32_bf16(af[m], bfr[n], acc[m][n], 0, 0, 0);
        __syncthreads();
    }

    int orow0 = bm + wr * 64;
    int ocol0 = bn + wc * 64;
#pragma unroll
    for (int m = 0; m < 4; ++m) {
        int row = orow0 + m * 16 + (l >> 4) * 4;
#pragma unroll
        for (int n = 0; n < 4; ++n) {
            int col = ocol0 + n * 16 + (l & 15);
            float bv = bias[col];
#pragma unroll
            for (int r = 0; r < 4; ++r) {
                float v = acc[m][n][r] + bv;
                if (OUT_F32)
                    ((float*)C)[(long)(row + r) * N + col] = v;
                else
                    ((bf16*)C)[(long)(row + r) * N + col] = (bf16)v;
            }
        }
    }
}

// ---------------- QKV: rmsnorm + rope + v-transpose ----------------
// q output is pre-scaled by 0.125 * log2(e) so attention softmax can use exp2.
__global__ __launch_bounds__(64) void qkv_kernel(const bf16* __restrict__ h,
                                                 const float* __restrict__ pe,
                                                 const float* __restrict__ qsc_,
                                                 const float* __restrict__ ksc_,
                                                 bf16* __restrict__ qo,
                                                 bf16* __restrict__ ko,
                                                 bf16* __restrict__ vTo) {
    int t = blockIdx.x;
    int b = t >> 11;
    int lpos = t & 2047;
    int d = threadIdx.x;
    const bf16* hrow = h + (long)t * 7168;
    float pe0 = pe[lpos * 128 + (d >> 1) * 4 + (d & 1) * 2 + 0];
    float pe1 = pe[lpos * 128 + (d >> 1) * 4 + (d & 1) * 2 + 1];
    float qsc = qsc_[d], ksc = ksc_[d];
#pragma unroll 1
    for (int hh = 0; hh < 16; ++hh) {
        float qv = (float)hrow[hh * 64 + d];
        float kv = (float)hrow[1024 + hh * 64 + d];
        float ssq = qv * qv, ssk = kv * kv;
#pragma unroll
        for (int off = 1; off < 64; off <<= 1) {
            ssq += __shfl_xor(ssq, off, 64);
            ssk += __shfl_xor(ssk, off, 64);
        }
        float qn = qv * rsqrtf(ssq * (1.0f / 64.0f) + 1e-6f) * qsc;
        float kn = kv * rsqrtf(ssk * (1.0f / 64.0f) + 1e-6f) * ksc;
        float qe = __shfl(qn, d & 62, 64), qodd = __shfl(qn, d | 1, 64);
        float ke = __shfl(kn, d & 62, 64), kodd = __shfl(kn, d | 1, 64);
        float qr = (pe0 * qe + pe1 * qodd) * 0.18033688011112042f;  // 0.125*log2e
        float kr = pe0 * ke + pe1 * kodd;
        long base = ((long)(b * 16 + hh) * 2048 + lpos) * 64 + d;
        qo[base] = (bf16)qr;
        ko[base] = (bf16)kr;
        vTo[((long)(b * 16 + hh) * 64 + d) * 2048 + lpos] = hrow[2048 + hh * 64 + d];
    }
}

// ---------------- GELU ----------------
__global__ void gelu_kernel(const bf16* __restrict__ h, bf16* __restrict__ cat) {
    long e = ((long)blockIdx.x * 256 + threadIdx.x) * 8;
    int t = (int)(e >> 12);
    int j = (int)(e & 4095);
    bf16x8 v = *(const bf16x8*)&h[(long)t * 7168 + 3072 + j];
    bf16x8 o;
#pragma unroll
    for (int r = 0; r < 8; ++r) {
        float x = (float)v[r];
        float g = 0.5f * x * (1.0f + tanhf(0.7978845608028654f * (x + 0.044715f * x * x * x)));
        o[r] = (bf16)g;
    }
    *(bf16x8*)&cat[(long)t * 5120 + 1024 + j] = o;
}

// ---------------- Flash attention, swapped-QK^T 32x32, LDS-routed P ----------------
// Grid: 256 blocks of 512 threads. bh = blockIdx&31, qblk = blockIdx>>5.
// 8 waves x 32 q-rows. KVBLK = 64. S^T = mfma(K, Q): lane owns q = l&31; regs hold
// kv = (r&3)+8*(r>>2)+4*(l>>5) (+32 for second mfma). P is written to per-wave LDS
// at C/D-derived kv addresses and read back as A-fragments with the SAME pattern
// used for V (and K) — so any per-lane k-order permutation of the MFMA operand
// layout cancels between A and B. Online softmax in exp2 domain, defer-max THR=8.
__global__ __launch_bounds__(512) void attn_kernel(const bf16* __restrict__ qg,
                                                   const bf16* __restrict__ kg_,
                                                   const bf16* __restrict__ vT,
                                                   bf16* __restrict__ cat) {
    __shared__ __align__(16) char lds[65536];
    char* Kl0 = lds;                 // [64][128B] swizzled
    char* Kl1 = lds + 8192;
    char* Vl0 = lds + 16384;         // V^T [d=64][128B] swizzled
    char* Vl1 = lds + 24576;

    int bidx = blockIdx.x;
    int bh = bidx & 31;
    int qblk = bidx >> 5;
    int b = bh >> 4, hh = bh & 15;
    int tid = threadIdx.x;
    int wv = tid >> 6, l = tid & 63;
    int h = l >> 5, ln = l & 31;
    int sw = (ln & 7) << 4;                  // read-side XOR swizzle

    char* Pw = lds + 32768 + wv * 4096;      // per-wave P [32 q][64 kv] bf16, swizzled

    // Q fragments: lane holds Q[q0+ln][ds*16 + h*8 .. +8]
    const bf16* qbase = qg + ((long)bh * 2048 + qblk * 256 + wv * 32 + ln) * 64 + h * 8;
    bf16x8 qf[4];
#pragma unroll
    for (int ds = 0; ds < 4; ++ds) qf[ds] = *(const bf16x8*)(qbase + ds * 16);

    f32x16 Oa0 = {}, Oa1 = {};
    float m = -1e30f, lsum = 0.0f;

    // staging assignment: thread -> (row kr, 16B granule kg)
    int kr = tid >> 3, kg = tid & 7;
    int swb = (kg * 16) ^ ((kr & 7) << 4);
    const bf16* gK = kg_ + ((long)bh * 2048 + kr) * 64 + kg * 8;
    const bf16* gV = vT + ((long)bh * 64 + kr) * 2048 + kg * 8;

    // prologue: stage tile 0
    bf16x8 rk = *(const bf16x8*)gK;
    bf16x8 rv = *(const bf16x8*)gV;
    *(bf16x8*)(Kl0 + kr * 128 + swb) = rk;
    *(bf16x8*)(Vl0 + kr * 128 + swb) = rv;
    __syncthreads();

    int c = 0;
    for (int t = 0; t < 32; ++t) {
        if (t < 31) {   // prefetch next tile into regs; latency hides under compute
            rk = *(const bf16x8*)(gK + (long)(t + 1) * 4096);
            rv = *(const bf16x8*)(gV + (t + 1) * 64);
        }
        const char* Kc = c ? Kl1 : Kl0;
        const char* Vc = c ? Vl1 : Vl0;

        // ---- S^T = K @ Q^T (two 32-row kv tiles) ----
        f32x16 S0 = {}, S1 = {};
#pragma unroll
        for (int ds = 0; ds < 4; ++ds) {
            bf16x8 kf0 = *(const bf16x8*)(Kc + ln * 128 + ((ds * 32 + h * 16) ^ sw));
            bf16x8 kf1 = *(const bf16x8*)(Kc + (32 + ln) * 128 + ((ds * 32 + h * 16) ^ sw));
            S0 = __builtin_amdgcn_mfma_f32_32x32x16_bf16(kf0, qf[ds], S0, 0, 0, 0);
            S1 = __builtin_amdgcn_mfma_f32_32x32x16_bf16(kf1, qf[ds], S1, 0, 0, 0);
        }

        // ---- online softmax (lane-local row; values already in log2 domain) ----
        float tmax = S0[0];
#pragma unroll
        for (int r = 1; r < 16; ++r) tmax = fmaxf(tmax, S0[r]);
#pragma unroll
        for (int r = 0; r < 16; ++r) tmax = fmaxf(tmax, S1[r]);
        tmax = fmaxf(tmax, __shfl_xor(tmax, 32, 64));

        if (!__all(tmax - m <= 8.0f)) {     // defer-max (T13)
            float mn = fmaxf(m, tmax);
            float es = ex2(m - mn);
            lsum *= es;
            m = mn;
#pragma unroll
            for (int r = 0; r < 16; ++r) {
                int rowq = (r & 3) + 8 * (r >> 2) + 4 * h;
                float esr = __shfl(es, rowq, 64);
                Oa0[r] *= esr;
                Oa1[r] *= esr;
            }
        }

        // ---- p = exp2(S - m); write to per-wave LDS at C/D-derived kv addresses ----
        float ps = 0.0f;
#pragma unroll
        for (int kvt = 0; kvt < 2; ++kvt) {
            float p[16];
#pragma unroll
            for (int r = 0; r < 16; ++r) {
                float v = ex2((kvt ? S1[r] : S0[r]) - m);
                p[r] = v;
                ps += v;
            }
#pragma unroll
            for (int i = 0; i < 8; ++i) {
                union { bf16 bb[2]; unsigned u; } pr;
                pr.bb[0] = (bf16)p[2 * i];
                pr.bb[1] = (bf16)p[2 * i + 1];
                int kv = ((2 * i) & 3) + 8 * (i >> 1) + 4 * h + 32 * kvt;   // even
                *(unsigned*)(Pw + ln * 128 + ((kv * 2) ^ sw)) = pr.u;
            }
        }
        lsum += ps + __shfl_xor(ps, 32, 64);

        // order P-writes before P-reads (same wave; no __syncthreads needed)
        asm volatile("s_waitcnt lgkmcnt(0)" ::: "memory");

        bf16x8 pa[4];
#pragma unroll
        for (int s = 0; s < 4; ++s)
            pa[s] = *(const bf16x8*)(Pw + ln * 128 + ((s * 32 + h * 16) ^ sw));

        // ---- PV: Oa += P @ V (V^T rows read with identical pattern) ----
#pragma unroll
        for (int s = 0; s < 4; ++s) {
            bf16x8 vf0 = *(const bf16x8*)(Vc + ln * 128 + ((s * 32 + h * 16) ^ sw));
            bf16x8 vf1 = *(const bf16x8*)(Vc + (32 + ln) * 128 + ((s * 32 + h * 16) ^ sw));
            Oa0 = __builtin_amdgcn_mfma_f32_32x32x16_bf16(pa[s], vf0, Oa0, 0, 0, 0);
            Oa1 = __builtin_amdgcn_mfma_f32_32x32x16_bf16(pa[s], vf1, Oa1, 0, 0, 0);
        }

        __syncthreads();
        if (t < 31) {
            char* Kn = c ? Kl0 : Kl1;
            char* Vn = c ? Vl0 : Vl1;
            *(bf16x8*)(Kn + kr * 128 + swb) = rk;
            *(bf16x8*)(Vn + kr * 128 + swb) = rv;
        }
        __syncthreads();
        c ^= 1;
    }

    // ---- epilogue: normalize + write ----
#pragma unroll
    for (int r = 0; r < 16; ++r) {
        int rowq = (r & 3) + 8 * (r >> 2) + 4 * h;
        float ls = __shfl(lsum, rowq, 64);
        float inv = 1.0f / ls;
        long trow = (long)b * 2048 + qblk * 256 + wv * 32 + rowq;
        cat[trow * 5120 + hh * 64 + ln] = (bf16)(Oa0[r] * inv);
        cat[trow * 5120 + hh * 64 + 32 + ln] = (bf16)(Oa1[r] * inv);
    }
}

// ---------------- launch ----------------

extern "C" void kernel_launch(void* const* d_in, const int* in_sizes, int n_in,
                              void* d_out, int out_size, void* d_ws, size_t ws_size,
                              hipStream_t stream) {
    const float* x  = (const float*)d_in[0];
    const float* pe = (const float*)d_in[1];
    const float* W1 = (const float*)d_in[2];
    const float* b1 = (const float*)d_in[3];
    const float* W2 = (const float*)d_in[4];
    const float* b2 = (const float*)d_in[5];
    const float* qs = (const float*)d_in[6];
    const float* ks = (const float*)d_in[7];
    float* out = (float*)d_out;

    char* ws = (char*)d_ws;
    bf16* xb  = (bf16*)(ws);                  // 4096*1024*2      =  8388608
    bf16* w1t = (bf16*)(ws + 8388608);        // 7168*1024*2      = 14680064
    bf16* w2t = (bf16*)(ws + 23068672);       // 1024*5120*2      = 10485760
    bf16* h   = (bf16*)(ws + 33554432);       // 4096*7168*2      = 58720256
    bf16* qb  = (bf16*)(ws + 92274688);       // 32*2048*64*2     =  8388608
    bf16* kb  = (bf16*)(ws + 100663296);      //                  =  8388608
    bf16* vT  = (bf16*)(ws + 109051904);      //                  =  8388608
    bf16* cat = (bf16*)(ws + 117440512);      // 4096*5120*2      = 41943040

    f2b_kernel<<<4096, 256, 0, stream>>>(x, xb, 4194304L);
    transpose_f2b<<<dim3(224, 32), 256, 0, stream>>>(W1, w1t, 1024, 7168);
    transpose_f2b<<<dim3(32, 160), 256, 0, stream>>>(W2, w2t, 5120, 1024);

    gemm_bt<false><<<dim3(32, 56), 256, 0, stream>>>(xb, w1t, b1, h, 4096, 7168, 1024);

    qkv_kernel<<<4096, 64, 0, stream>>>(h, pe, qs, ks, qb, kb, vT);
    gelu_kernel<<<8192, 256, 0, stream>>>(h, cat);

    attn_kernel<<<256, 512, 0, stream>>>(qb, kb, vT, cat);

    gemm_bt<true><<<dim3(32, 8), 256, 0, stream>>>(cat, w2t, b2, out, 4096, 1024, 5120);
}

// Round 4
// 298.285 us; speedup vs baseline: 1.4066x; 1.1209x over previous
//
#include <hip/hip_runtime.h>

typedef __bf16 bf16;
typedef __bf16 bf16x8 __attribute__((ext_vector_type(8)));
typedef float f32x4 __attribute__((ext_vector_type(4)));
typedef float f32x16 __attribute__((ext_vector_type(16)));

#define GLDS16(gp, lp) __builtin_amdgcn_global_load_lds( \
    (__attribute__((address_space(1))) void*)(gp), \
    (__attribute__((address_space(3))) void*)(lp), 16, 0, 0)

__device__ inline float ex2(float x) { return exp2f(x); }

// ---------------- conversion kernels ----------------

__global__ void f2b_kernel(const float* __restrict__ src, bf16* __restrict__ dst, long n) {
    long i = ((long)blockIdx.x * 256 + threadIdx.x) * 4;
    if (i + 3 < n) {
        float4 v = *(const float4*)&src[i];
        dst[i + 0] = (bf16)v.x;
        dst[i + 1] = (bf16)v.y;
        dst[i + 2] = (bf16)v.z;
        dst[i + 3] = (bf16)v.w;
    }
}

// W: K x N (f32, row-major) -> WT: N x K (bf16, row-major)
__global__ __launch_bounds__(256) void transpose_f2b(const float* __restrict__ W,
                                                     bf16* __restrict__ WT,
                                                     int K, int N) {
    __shared__ float tile[32][33];
    int tx = threadIdx.x & 31;
    int ty = threadIdx.x >> 5;               // 0..7
    int n0 = blockIdx.x * 32;
    int k0 = blockIdx.y * 32;
#pragma unroll
    for (int i = 0; i < 4; ++i)
        tile[ty + i * 8][tx] = W[(long)(k0 + ty + i * 8) * N + n0 + tx];
    __syncthreads();
#pragma unroll
    for (int i = 0; i < 4; ++i)
        WT[(long)(n0 + ty + i * 8) * K + k0 + tx] = (bf16)tile[tx][ty + i * 8];
}

// ---------------- GEMM (m97-style 128x128, BK=32) ----------------
template <bool OUT_F32>
__global__ __launch_bounds__(256) void gemm_bt(const bf16* __restrict__ A,
                                               const bf16* __restrict__ BT,
                                               const float* __restrict__ bias,
                                               void* __restrict__ C,
                                               int M, int N, int K) {
    __shared__ bf16 Asm[128 * 32];
    __shared__ bf16 Bsm[128 * 32];
    int tid = threadIdx.x;
    int w = tid >> 6, l = tid & 63;
    int wr = w >> 1, wc = w & 1;
    int bm = blockIdx.x * 128;
    int bn = blockIdx.y * 128;

    f32x4 acc[4][4] = {};

    int arow = l >> 2;
    int acol = (l & 3) * 8;
    int fr = l & 15;
    int fk = (l >> 4) * 8;

    int nk = K >> 5;
    for (int kt = 0; kt < nk; ++kt) {
        int k0 = kt * 32;
#pragma unroll
        for (int it = 0; it < 2; ++it) {
            int c = it * 4 + w;
            const bf16* ga = A + (long)(bm + c * 16 + arow) * K + k0 + acol;
            GLDS16(ga, &Asm[c * 512]);
            const bf16* gb = BT + (long)(bn + c * 16 + arow) * K + k0 + acol;
            GLDS16(gb, &Bsm[c * 512]);
        }
        asm volatile("s_waitcnt vmcnt(0)" ::: "memory");
        __syncthreads();

        bf16x8 af[4], bfr[4];
#pragma unroll
        for (int m = 0; m < 4; ++m)
            af[m] = *(const bf16x8*)&Asm[(wr * 64 + m * 16 + fr) * 32 + fk];
#pragma unroll
        for (int n = 0; n < 4; ++n)
            bfr[n] = *(const bf16x8*)&Bsm[(wc * 64 + n * 16 + fr) * 32 + fk];
#pragma unroll
        for (int m = 0; m < 4; ++m)
#pragma unroll
            for (int n = 0; n < 4; ++n)
                acc[m][n] = __builtin_amdgcn_mfma_f32_16x16x32_bf16(af[m], bfr[n], acc[m][n], 0, 0, 0);
        __syncthreads();
    }

    int orow0 = bm + wr * 64;
    int ocol0 = bn + wc * 64;
#pragma unroll
    for (int m = 0; m < 4; ++m) {
        int row = orow0 + m * 16 + (l >> 4) * 4;
#pragma unroll
        for (int n = 0; n < 4; ++n) {
            int col = ocol0 + n * 16 + (l & 15);
            float bv = bias[col];
#pragma unroll
            for (int r = 0; r < 4; ++r) {
                float v = acc[m][n][r] + bv;
                if (OUT_F32)
                    ((float*)C)[(long)(row + r) * N + col] = v;
                else
                    ((bf16*)C)[(long)(row + r) * N + col] = (bf16)v;
            }
        }
    }
}

// ---------------- split-K GEMM: partials[z][M][N] f32, no bias ----------------
__global__ __launch_bounds__(256) void gemm_bt_splitk(const bf16* __restrict__ A,
                                                      const bf16* __restrict__ BT,
                                                      float* __restrict__ part,
                                                      int M, int N, int K, int kchunk) {
    __shared__ bf16 Asm[128 * 32];
    __shared__ bf16 Bsm[128 * 32];
    int tid = threadIdx.x;
    int w = tid >> 6, l = tid & 63;
    int wr = w >> 1, wc = w & 1;
    int bm = blockIdx.x * 128;
    int bn = blockIdx.y * 128;
    int kz = blockIdx.z;

    f32x4 acc[4][4] = {};

    int arow = l >> 2;
    int acol = (l & 3) * 8;
    int fr = l & 15;
    int fk = (l >> 4) * 8;

    int nk = kchunk >> 5;
    for (int kt = 0; kt < nk; ++kt) {
        int k0 = kz * kchunk + kt * 32;
#pragma unroll
        for (int it = 0; it < 2; ++it) {
            int c = it * 4 + w;
            const bf16* ga = A + (long)(bm + c * 16 + arow) * K + k0 + acol;
            GLDS16(ga, &Asm[c * 512]);
            const bf16* gb = BT + (long)(bn + c * 16 + arow) * K + k0 + acol;
            GLDS16(gb, &Bsm[c * 512]);
        }
        asm volatile("s_waitcnt vmcnt(0)" ::: "memory");
        __syncthreads();

        bf16x8 af[4], bfr[4];
#pragma unroll
        for (int m = 0; m < 4; ++m)
            af[m] = *(const bf16x8*)&Asm[(wr * 64 + m * 16 + fr) * 32 + fk];
#pragma unroll
        for (int n = 0; n < 4; ++n)
            bfr[n] = *(const bf16x8*)&Bsm[(wc * 64 + n * 16 + fr) * 32 + fk];
#pragma unroll
        for (int m = 0; m < 4; ++m)
#pragma unroll
            for (int n = 0; n < 4; ++n)
                acc[m][n] = __builtin_amdgcn_mfma_f32_16x16x32_bf16(af[m], bfr[n], acc[m][n], 0, 0, 0);
        __syncthreads();
    }

    float* cz = part + (long)kz * M * N;
    int orow0 = bm + wr * 64;
    int ocol0 = bn + wc * 64;
#pragma unroll
    for (int m = 0; m < 4; ++m) {
        int row = orow0 + m * 16 + (l >> 4) * 4;
#pragma unroll
        for (int n = 0; n < 4; ++n) {
            int col = ocol0 + n * 16 + (l & 15);
#pragma unroll
            for (int r = 0; r < 4; ++r)
                cz[(long)(row + r) * N + col] = acc[m][n][r];
        }
    }
}

// out[i] = b2[i & 1023] + sum_z part[z][i]   (N = 1024)
__global__ __launch_bounds__(256) void reduce4_kernel(const float* __restrict__ part,
                                                      const float* __restrict__ b2,
                                                      float* __restrict__ out) {
    const long stride4 = 4096L * 1024 / 4;
#pragma unroll
    for (int it = 0; it < 2; ++it) {
        long i4 = (long)blockIdx.x * 512 + it * 256 + threadIdx.x;
        float4 s = *(const float4*)&b2[(i4 * 4) & 1023];
        const float4* p = (const float4*)part;
#pragma unroll
        for (int z = 0; z < 4; ++z) {
            float4 v = p[z * stride4 + i4];
            s.x += v.x; s.y += v.y; s.z += v.z; s.w += v.w;
        }
        *(float4*)&out[i4 * 4] = s;
    }
}

// ---------------- QKV: rmsnorm + rope (V untouched) ----------------
// q output is pre-scaled by 0.125 * log2(e) so attention softmax can use exp2.
__global__ __launch_bounds__(256) void qkv_kernel(const bf16* __restrict__ h,
                                                  const float* __restrict__ pe,
                                                  const float* __restrict__ qsc_,
                                                  const float* __restrict__ ksc_,
                                                  bf16* __restrict__ qo,
                                                  bf16* __restrict__ ko) {
    int t = blockIdx.x;
    int b = t >> 11;
    int lpos = t & 2047;
    int wv = threadIdx.x >> 6;
    int d = threadIdx.x & 63;
    const bf16* hrow = h + (long)t * 7168;
    float pe0 = pe[lpos * 128 + (d >> 1) * 4 + (d & 1) * 2 + 0];
    float pe1 = pe[lpos * 128 + (d >> 1) * 4 + (d & 1) * 2 + 1];
    float qsc = qsc_[d], ksc = ksc_[d];
#pragma unroll 1
    for (int it = 0; it < 4; ++it) {
        int hh = wv * 4 + it;
        float qv = (float)hrow[hh * 64 + d];
        float kv = (float)hrow[1024 + hh * 64 + d];
        float ssq = qv * qv, ssk = kv * kv;
#pragma unroll
        for (int off = 1; off < 64; off <<= 1) {
            ssq += __shfl_xor(ssq, off, 64);
            ssk += __shfl_xor(ssk, off, 64);
        }
        float qn = qv * rsqrtf(ssq * (1.0f / 64.0f) + 1e-6f) * qsc;
        float kn = kv * rsqrtf(ssk * (1.0f / 64.0f) + 1e-6f) * ksc;
        float qe = __shfl(qn, d & 62, 64), qodd = __shfl(qn, d | 1, 64);
        float ke = __shfl(kn, d & 62, 64), kodd = __shfl(kn, d | 1, 64);
        float qr = (pe0 * qe + pe1 * qodd) * 0.18033688011112042f;  // 0.125*log2e
        float kr = pe0 * ke + pe1 * kodd;
        long base = ((long)(b * 16 + hh) * 2048 + lpos) * 64 + d;
        qo[base] = (bf16)qr;
        ko[base] = (bf16)kr;
    }
}

// ---------------- V transpose: h[:, 2048:3072] -> vT[bh][d][lpos] ----------------
__global__ __launch_bounds__(256) void vtrans_kernel(const bf16* __restrict__ h,
                                                     bf16* __restrict__ vT) {
    __shared__ unsigned short tile[64 * 65];
    int bh = blockIdx.x;
    int b = bh >> 4, hh = bh & 15;
    int l0 = blockIdx.y * 64;
    int tid = threadIdx.x;

    // load 64 lpos-rows x 64 d (coalesced 16B), store to LDS stride-65
    int r = tid >> 3, c = tid & 7;   // r: 0..31, c: 0..7
#pragma unroll
    for (int p = 0; p < 2; ++p) {
        int row = r + p * 32;
        const bf16* src = h + (long)(b * 2048 + l0 + row) * 7168 + 2048 + hh * 64 + c * 8;
        bf16x8 v = *(const bf16x8*)src;
        union { bf16x8 v; unsigned short s[8]; } u; u.v = v;
#pragma unroll
        for (int e = 0; e < 8; ++e) tile[row * 65 + c * 8 + e] = u.s[e];
    }
    __syncthreads();

    // write 64 d-rows x 64 lpos (coalesced 16B)
#pragma unroll
    for (int p = 0; p < 2; ++p) {
        int idx = tid + p * 256;
        int d = idx >> 3, kg = idx & 7;
        union { bf16x8 v; unsigned short s[8]; } u;
#pragma unroll
        for (int e = 0; e < 8; ++e) u.s[e] = tile[(kg * 8 + e) * 65 + d];
        *(bf16x8*)&vT[((long)bh * 64 + d) * 2048 + l0 + kg * 8] = u.v;
    }
}

// ---------------- GELU ----------------
__global__ void gelu_kernel(const bf16* __restrict__ h, bf16* __restrict__ cat) {
    long e = ((long)blockIdx.x * 256 + threadIdx.x) * 8;
    int t = (int)(e >> 12);
    int j = (int)(e & 4095);
    bf16x8 v = *(const bf16x8*)&h[(long)t * 7168 + 3072 + j];
    bf16x8 o;
#pragma unroll
    for (int r = 0; r < 8; ++r) {
        float x = (float)v[r];
        float g = 0.5f * x * (1.0f + tanhf(0.7978845608028654f * (x + 0.044715f * x * x * x)));
        o[r] = (bf16)g;
    }
    *(bf16x8*)&cat[(long)t * 5120 + 1024 + j] = o;
}

// ---------------- Flash attention, swapped-QK^T 32x32, LDS-routed P ----------------
__global__ __launch_bounds__(512) void attn_kernel(const bf16* __restrict__ qg,
                                                   const bf16* __restrict__ kg_,
                                                   const bf16* __restrict__ vT,
                                                   bf16* __restrict__ cat) {
    __shared__ __align__(16) char lds[65536];
    char* Kl0 = lds;                 // [64][128B] swizzled
    char* Kl1 = lds + 8192;
    char* Vl0 = lds + 16384;         // V^T [d=64][128B] swizzled
    char* Vl1 = lds + 24576;

    int bidx = blockIdx.x;
    int bh = bidx & 31;
    int qblk = bidx >> 5;
    int b = bh >> 4, hh = bh & 15;
    int tid = threadIdx.x;
    int wv = tid >> 6, l = tid & 63;
    int h = l >> 5, ln = l & 31;
    int sw = (ln & 7) << 4;                  // read-side XOR swizzle

    char* Pw = lds + 32768 + wv * 4096;      // per-wave P [32 q][64 kv] bf16, swizzled

    const bf16* qbase = qg + ((long)bh * 2048 + qblk * 256 + wv * 32 + ln) * 64 + h * 8;
    bf16x8 qf[4];
#pragma unroll
    for (int ds = 0; ds < 4; ++ds) qf[ds] = *(const bf16x8*)(qbase + ds * 16);

    f32x16 Oa0 = {}, Oa1 = {};
    float m = -1e30f, lsum = 0.0f;

    int kr = tid >> 3, kg = tid & 7;
    int swb = (kg * 16) ^ ((kr & 7) << 4);
    const bf16* gK = kg_ + ((long)bh * 2048 + kr) * 64 + kg * 8;
    const bf16* gV = vT + ((long)bh * 64 + kr) * 2048 + kg * 8;

    bf16x8 rk = *(const bf16x8*)gK;
    bf16x8 rv = *(const bf16x8*)gV;
    *(bf16x8*)(Kl0 + kr * 128 + swb) = rk;
    *(bf16x8*)(Vl0 + kr * 128 + swb) = rv;
    __syncthreads();

    int c = 0;
    for (int t = 0; t < 32; ++t) {
        if (t < 31) {
            rk = *(const bf16x8*)(gK + (long)(t + 1) * 4096);
            rv = *(const bf16x8*)(gV + (t + 1) * 64);
        }
        const char* Kc = c ? Kl1 : Kl0;
        const char* Vc = c ? Vl1 : Vl0;

        f32x16 S0 = {}, S1 = {};
#pragma unroll
        for (int ds = 0; ds < 4; ++ds) {
            bf16x8 kf0 = *(const bf16x8*)(Kc + ln * 128 + ((ds * 32 + h * 16) ^ sw));
            bf16x8 kf1 = *(const bf16x8*)(Kc + (32 + ln) * 128 + ((ds * 32 + h * 16) ^ sw));
            S0 = __builtin_amdgcn_mfma_f32_32x32x16_bf16(kf0, qf[ds], S0, 0, 0, 0);
            S1 = __builtin_amdgcn_mfma_f32_32x32x16_bf16(kf1, qf[ds], S1, 0, 0, 0);
        }

        float tmax = S0[0];
#pragma unroll
        for (int r = 1; r < 16; ++r) tmax = fmaxf(tmax, S0[r]);
#pragma unroll
        for (int r = 0; r < 16; ++r) tmax = fmaxf(tmax, S1[r]);
        tmax = fmaxf(tmax, __shfl_xor(tmax, 32, 64));

        if (!__all(tmax - m <= 8.0f)) {
            float mn = fmaxf(m, tmax);
            float es = ex2(m - mn);
            lsum *= es;
            m = mn;
#pragma unroll
            for (int r = 0; r < 16; ++r) {
                int rowq = (r & 3) + 8 * (r >> 2) + 4 * h;
                float esr = __shfl(es, rowq, 64);
                Oa0[r] *= esr;
                Oa1[r] *= esr;
            }
        }

        float ps = 0.0f;
#pragma unroll
        for (int kvt = 0; kvt < 2; ++kvt) {
            float p[16];
#pragma unroll
            for (int r = 0; r < 16; ++r) {
                float v = ex2((kvt ? S1[r] : S0[r]) - m);
                p[r] = v;
                ps += v;
            }
#pragma unroll
            for (int i = 0; i < 8; ++i) {
                union { bf16 bb[2]; unsigned u; } pr;
                pr.bb[0] = (bf16)p[2 * i];
                pr.bb[1] = (bf16)p[2 * i + 1];
                int kv = ((2 * i) & 3) + 8 * (i >> 1) + 4 * h + 32 * kvt;   // even
                *(unsigned*)(Pw + ln * 128 + ((kv * 2) ^ sw)) = pr.u;
            }
        }
        lsum += ps + __shfl_xor(ps, 32, 64);

        asm volatile("s_waitcnt lgkmcnt(0)" ::: "memory");

        bf16x8 pa[4];
#pragma unroll
        for (int s = 0; s < 4; ++s)
            pa[s] = *(const bf16x8*)(Pw + ln * 128 + ((s * 32 + h * 16) ^ sw));

#pragma unroll
        for (int s = 0; s < 4; ++s) {
            bf16x8 vf0 = *(const bf16x8*)(Vc + ln * 128 + ((s * 32 + h * 16) ^ sw));
            bf16x8 vf1 = *(const bf16x8*)(Vc + (32 + ln) * 128 + ((s * 32 + h * 16) ^ sw));
            Oa0 = __builtin_amdgcn_mfma_f32_32x32x16_bf16(pa[s], vf0, Oa0, 0, 0, 0);
            Oa1 = __builtin_amdgcn_mfma_f32_32x32x16_bf16(pa[s], vf1, Oa1, 0, 0, 0);
        }

        __syncthreads();
        if (t < 31) {
            char* Kn = c ? Kl0 : Kl1;
            char* Vn = c ? Vl0 : Vl1;
            *(bf16x8*)(Kn + kr * 128 + swb) = rk;
            *(bf16x8*)(Vn + kr * 128 + swb) = rv;
        }
        __syncthreads();
        c ^= 1;
    }

#pragma unroll
    for (int r = 0; r < 16; ++r) {
        int rowq = (r & 3) + 8 * (r >> 2) + 4 * h;
        float ls = __shfl(lsum, rowq, 64);
        float inv = 1.0f / ls;
        long trow = (long)b * 2048 + qblk * 256 + wv * 32 + rowq;
        cat[trow * 5120 + hh * 64 + ln] = (bf16)(Oa0[r] * inv);
        cat[trow * 5120 + hh * 64 + 32 + ln] = (bf16)(Oa1[r] * inv);
    }
}

// ---------------- launch ----------------

extern "C" void kernel_launch(void* const* d_in, const int* in_sizes, int n_in,
                              void* d_out, int out_size, void* d_ws, size_t ws_size,
                              hipStream_t stream) {
    const float* x  = (const float*)d_in[0];
    const float* pe = (const float*)d_in[1];
    const float* W1 = (const float*)d_in[2];
    const float* b1 = (const float*)d_in[3];
    const float* W2 = (const float*)d_in[4];
    const float* b2 = (const float*)d_in[5];
    const float* qs = (const float*)d_in[6];
    const float* ks = (const float*)d_in[7];
    float* out = (float*)d_out;

    char* ws = (char*)d_ws;
    bf16* xb  = (bf16*)(ws);                  // 4096*1024*2      =  8388608
    bf16* w1t = (bf16*)(ws + 8388608);        // 7168*1024*2      = 14680064
    bf16* w2t = (bf16*)(ws + 23068672);       // 1024*5120*2      = 10485760
    bf16* h   = (bf16*)(ws + 33554432);       // 4096*7168*2      = 58720256
    bf16* qb  = (bf16*)(ws + 92274688);       // 32*2048*64*2     =  8388608
    bf16* kb  = (bf16*)(ws + 100663296);      //                  =  8388608
    bf16* vT  = (bf16*)(ws + 109051904);      //                  =  8388608
    bf16* cat = (bf16*)(ws + 117440512);      // 4096*5120*2      = 41943040
    // split-K partials (4 x 4096 x 1024 f32 = 67108864 B) reuse the h/qb/kb
    // region — h, qb, kb are all dead by the time gemm_bt_splitk runs.
    float* part = (float*)(ws + 33554432);

    f2b_kernel<<<4096, 256, 0, stream>>>(x, xb, 4194304L);
    transpose_f2b<<<dim3(224, 32), 256, 0, stream>>>(W1, w1t, 1024, 7168);
    transpose_f2b<<<dim3(32, 160), 256, 0, stream>>>(W2, w2t, 5120, 1024);

    gemm_bt<false><<<dim3(32, 56), 256, 0, stream>>>(xb, w1t, b1, h, 4096, 7168, 1024);

    qkv_kernel<<<4096, 256, 0, stream>>>(h, pe, qs, ks, qb, kb);
    vtrans_kernel<<<dim3(32, 32), 256, 0, stream>>>(h, vT);
    gelu_kernel<<<8192, 256, 0, stream>>>(h, cat);

    attn_kernel<<<256, 512, 0, stream>>>(qb, kb, vT, cat);

    gemm_bt_splitk<<<dim3(32, 8, 4), 256, 0, stream>>>(cat, w2t, part, 4096, 1024, 5120, 1280);
    reduce4_kernel<<<2048, 256, 0, stream>>>(part, b2, out);
}

// Round 5
// 290.462 us; speedup vs baseline: 1.4445x; 1.0269x over previous
//
#include <hip/hip_runtime.h>

typedef __bf16 bf16;
typedef __bf16 bf16x8 __attribute__((ext_vector_type(8)));
typedef float f32x4 __attribute__((ext_vector_type(4)));
typedef float f32x16 __attribute__((ext_vector_type(16)));

#define GLDS16(gp, lp) __builtin_amdgcn_global_load_lds( \
    (__attribute__((address_space(1))) void*)(gp), \
    (__attribute__((address_space(3))) void*)(lp), 16, 0, 0)

#define BARRIER() asm volatile("s_barrier" ::: "memory")
#define LGKM0_FENCE() do { asm volatile("s_waitcnt lgkmcnt(0)" ::: "memory"); \
                           __builtin_amdgcn_sched_barrier(0); } while (0)

__device__ inline float ex2(float x) { return exp2f(x); }

// ---------------- conversion kernels ----------------

__global__ void f2b_kernel(const float* __restrict__ src, bf16* __restrict__ dst, long n) {
    long i = ((long)blockIdx.x * 256 + threadIdx.x) * 4;
    if (i + 3 < n) {
        float4 v = *(const float4*)&src[i];
        dst[i + 0] = (bf16)v.x;
        dst[i + 1] = (bf16)v.y;
        dst[i + 2] = (bf16)v.z;
        dst[i + 3] = (bf16)v.w;
    }
}

// W: K x N (f32, row-major) -> WT: N x K (bf16, row-major)
__global__ __launch_bounds__(256) void transpose_f2b(const float* __restrict__ W,
                                                     bf16* __restrict__ WT,
                                                     int K, int N) {
    __shared__ float tile[32][33];
    int tx = threadIdx.x & 31;
    int ty = threadIdx.x >> 5;
    int n0 = blockIdx.x * 32;
    int k0 = blockIdx.y * 32;
#pragma unroll
    for (int i = 0; i < 4; ++i)
        tile[ty + i * 8][tx] = W[(long)(k0 + ty + i * 8) * N + n0 + tx];
    __syncthreads();
#pragma unroll
    for (int i = 0; i < 4; ++i)
        WT[(long)(n0 + ty + i * 8) * K + k0 + tx] = (bf16)tile[tx][ty + i * 8];
}

// ---------------- 256x256 pipelined GEMM (BK=32, counted vmcnt, T3/T4/T5) ----
// EPI 0: C = A@BT^T + bias -> cols<3072 to h (bf16), cols>=3072 gelu -> cat
// EPI 1: f32 partials (split-K over blockIdx.z), no bias
template <int EPI>
__global__ __launch_bounds__(512, 2) void gemm256(const bf16* __restrict__ A_,
                                                  const bf16* __restrict__ BT_,
                                                  const float* __restrict__ bias,
                                                  void* __restrict__ C0,
                                                  void* __restrict__ C1,
                                                  int M, int N, int K, int kch) {
    __shared__ __align__(16) char ldsb[65536];   // [dbuf][A 16K | B 16K]

    int bx, by, k0base = 0;
    if (EPI == 0) {
        int bid = blockIdx.x;
        int swz = (bid & 7) * 56 + (bid >> 3);   // 448 blocks, XCD-bijective
        bx = swz & 15; by = swz >> 4;
    } else {
        bx = blockIdx.x; by = blockIdx.y;
        k0base = blockIdx.z * kch;
    }
    int bm = bx * 256, bn = by * 256;
    int NT = kch >> 5;

    int tid = threadIdx.x;
    int w = tid >> 6, l = tid & 63;
    int wr = w >> 2, wc = w & 3;                 // 2M x 4N waves
    int fr = l & 15, g = l >> 4;

    // staging thread -> (row, col8)
    int srow = tid >> 2;
    int scol = (tid & 3) * 8;
    const bf16* gA = A_ + (long)(bm + srow) * K + k0base + scol;
    const bf16* gB = BT_ + (long)(bn + srow) * K + k0base + scol;

    // per-lane LDS read offsets (64B rows)
    int abase = (wr * 128 + fr) * 64 + g * 16;
    int bbase = (wc * 64 + fr) * 64 + g * 16;

    f32x4 acc[8][4] = {};

    // ---- prologue: A(0),B(0) -> dbuf0 ; B(1) -> dbuf1 ----
    GLDS16(gA, ldsb + tid * 16);
    GLDS16(gA + (long)128 * K, ldsb + 8192 + tid * 16);
    GLDS16(gB, ldsb + 16384 + tid * 16);
    GLDS16(gB + (long)128 * K, ldsb + 16384 + 8192 + tid * 16);
    GLDS16(gB + 32, ldsb + 32768 + 16384 + tid * 16);
    GLDS16(gB + 32 + (long)128 * K, ldsb + 32768 + 16384 + 8192 + tid * 16);
    asm volatile("s_waitcnt vmcnt(2)" ::: "memory");
    BARRIER();

    for (int u = 0; u < NT; ++u) {
        const char* Ab = ldsb + (u & 1) * 32768;
        const char* Bb = Ab + 16384;
        int nxt = (~u) & 1;

        // ======== phase 0: B-frags + A m0..3, stage A(u+1) ========
        bf16x8 af[4], bfr[4];
#pragma unroll
        for (int i = 0; i < 4; ++i)
            af[i] = *(const bf16x8*)(Ab + abase + i * 1024);
#pragma unroll
        for (int n = 0; n < 4; ++n)
            bfr[n] = *(const bf16x8*)(Bb + bbase + n * 1024);
        if (u + 1 < NT) {
            const bf16* s = gA + (u + 1) * 32;
            GLDS16(s, ldsb + nxt * 32768 + tid * 16);
            GLDS16(s + (long)128 * K, ldsb + nxt * 32768 + 8192 + tid * 16);
        }
        BARRIER();
        LGKM0_FENCE();
        __builtin_amdgcn_s_setprio(1);
#pragma unroll
        for (int n = 0; n < 4; ++n)
#pragma unroll
            for (int i = 0; i < 4; ++i)
                acc[i][n] = __builtin_amdgcn_mfma_f32_16x16x32_bf16(af[i], bfr[n], acc[i][n], 0, 0, 0);
        __builtin_amdgcn_s_setprio(0);
        BARRIER();

        // ======== phase 1: A m4..7, stage B(u+2) ========
#pragma unroll
        for (int i = 0; i < 4; ++i)
            af[i] = *(const bf16x8*)(Ab + abase + (4 + i) * 1024);
        if (u + 2 < NT) {
            const bf16* s = gB + (u + 2) * 32;
            GLDS16(s, ldsb + (u & 1) * 32768 + 16384 + tid * 16);
            GLDS16(s + (long)128 * K, ldsb + (u & 1) * 32768 + 16384 + 8192 + tid * 16);
        }
        BARRIER();
        LGKM0_FENCE();
        __builtin_amdgcn_s_setprio(1);
#pragma unroll
        for (int n = 0; n < 4; ++n)
#pragma unroll
            for (int i = 0; i < 4; ++i)
                acc[4 + i][n] = __builtin_amdgcn_mfma_f32_16x16x32_bf16(af[i], bfr[n], acc[4 + i][n], 0, 0, 0);
        __builtin_amdgcn_s_setprio(0);
        if (u < NT - 2) {
            asm volatile("s_waitcnt vmcnt(2)" ::: "memory");
        } else {
            asm volatile("s_waitcnt vmcnt(0)" ::: "memory");
        }
        BARRIER();
    }

    // ---- epilogue ----
    int r4 = (l >> 4) * 4;
    if (EPI == 0) {
        bf16* hp = (bf16*)C0;
        bf16* cat = (bf16*)C1;
        bool gel = (bn >= 3072);
#pragma unroll
        for (int mi = 0; mi < 8; ++mi) {
            int row = bm + wr * 128 + mi * 16 + r4;
#pragma unroll
            for (int n = 0; n < 4; ++n) {
                int col = bn + wc * 64 + n * 16 + fr;
                float bv = bias[col];
#pragma unroll
                for (int r = 0; r < 4; ++r) {
                    float v = acc[mi][n][r] + bv;
                    if (gel) {
                        float gg = 0.5f * v * (1.0f + tanhf(0.7978845608028654f * (v + 0.044715f * v * v * v)));
                        cat[(long)(row + r) * 5120 + 1024 + col - 3072] = (bf16)gg;
                    } else {
                        hp[(long)(row + r) * N + col] = (bf16)v;
                    }
                }
            }
        }
    } else {
        float* cz = (float*)C0 + (long)blockIdx.z * M * N;
#pragma unroll
        for (int mi = 0; mi < 8; ++mi) {
            int row = bm + wr * 128 + mi * 16 + r4;
#pragma unroll
            for (int n = 0; n < 4; ++n) {
                int col = bn + wc * 64 + n * 16 + fr;
#pragma unroll
                for (int r = 0; r < 4; ++r)
                    cz[(long)(row + r) * N + col] = acc[mi][n][r];
            }
        }
    }
}

// out[i] = b2[i & 1023] + sum_z part[z][i]   (N = 1024)
__global__ __launch_bounds__(256) void reduce4_kernel(const float* __restrict__ part,
                                                      const float* __restrict__ b2,
                                                      float* __restrict__ out) {
    const long stride4 = 4096L * 1024 / 4;
#pragma unroll
    for (int it = 0; it < 2; ++it) {
        long i4 = (long)blockIdx.x * 512 + it * 256 + threadIdx.x;
        float4 s = *(const float4*)&b2[(i4 * 4) & 1023];
        const float4* p = (const float4*)part;
#pragma unroll
        for (int z = 0; z < 4; ++z) {
            float4 v = p[z * stride4 + i4];
            s.x += v.x; s.y += v.y; s.z += v.z; s.w += v.w;
        }
        *(float4*)&out[i4 * 4] = s;
    }
}

// ---------------- QKV: rmsnorm + rope ----------------
__global__ __launch_bounds__(256) void qkv_kernel(const bf16* __restrict__ h,
                                                  const float* __restrict__ pe,
                                                  const float* __restrict__ qsc_,
                                                  const float* __restrict__ ksc_,
                                                  bf16* __restrict__ qo,
                                                  bf16* __restrict__ ko) {
    int t = blockIdx.x;
    int b = t >> 11;
    int lpos = t & 2047;
    int wv = threadIdx.x >> 6;
    int d = threadIdx.x & 63;
    const bf16* hrow = h + (long)t * 7168;
    float pe0 = pe[lpos * 128 + (d >> 1) * 4 + (d & 1) * 2 + 0];
    float pe1 = pe[lpos * 128 + (d >> 1) * 4 + (d & 1) * 2 + 1];
    float qsc = qsc_[d], ksc = ksc_[d];
#pragma unroll 1
    for (int it = 0; it < 4; ++it) {
        int hh = wv * 4 + it;
        float qv = (float)hrow[hh * 64 + d];
        float kv = (float)hrow[1024 + hh * 64 + d];
        float ssq = qv * qv, ssk = kv * kv;
#pragma unroll
        for (int off = 1; off < 64; off <<= 1) {
            ssq += __shfl_xor(ssq, off, 64);
            ssk += __shfl_xor(ssk, off, 64);
        }
        float qn = qv * rsqrtf(ssq * (1.0f / 64.0f) + 1e-6f) * qsc;
        float kn = kv * rsqrtf(ssk * (1.0f / 64.0f) + 1e-6f) * ksc;
        float qe = __shfl(qn, d & 62, 64), qodd = __shfl(qn, d | 1, 64);
        float ke = __shfl(kn, d & 62, 64), kodd = __shfl(kn, d | 1, 64);
        float qr = (pe0 * qe + pe1 * qodd) * 0.18033688011112042f;  // 0.125*log2e
        float kr = pe0 * ke + pe1 * kodd;
        long base = ((long)(b * 16 + hh) * 2048 + lpos) * 64 + d;
        qo[base] = (bf16)qr;
        ko[base] = (bf16)kr;
    }
}

// ---------------- V transpose: h[:, 2048:3072] -> vT[bh][d][lpos] ----------------
__global__ __launch_bounds__(256) void vtrans_kernel(const bf16* __restrict__ h,
                                                     bf16* __restrict__ vT) {
    __shared__ unsigned short tile[64 * 65];
    int bh = blockIdx.x;
    int b = bh >> 4, hh = bh & 15;
    int l0 = blockIdx.y * 64;
    int tid = threadIdx.x;

    int r = tid >> 3, c = tid & 7;
#pragma unroll
    for (int p = 0; p < 2; ++p) {
        int row = r + p * 32;
        const bf16* src = h + (long)(b * 2048 + l0 + row) * 7168 + 2048 + hh * 64 + c * 8;
        bf16x8 v = *(const bf16x8*)src;
        union { bf16x8 v; unsigned short s[8]; } u; u.v = v;
#pragma unroll
        for (int e = 0; e < 8; ++e) tile[row * 65 + c * 8 + e] = u.s[e];
    }
    __syncthreads();
#pragma unroll
    for (int p = 0; p < 2; ++p) {
        int idx = tid + p * 256;
        int d = idx >> 3, kg = idx & 7;
        union { bf16x8 v; unsigned short s[8]; } u;
#pragma unroll
        for (int e = 0; e < 8; ++e) u.s[e] = tile[(kg * 8 + e) * 65 + d];
        *(bf16x8*)&vT[((long)bh * 64 + d) * 2048 + l0 + kg * 8] = u.v;
    }
}

// ---------------- Flash attention, swapped-QK^T 32x32, LDS-routed P ----------------
__global__ __launch_bounds__(512) void attn_kernel(const bf16* __restrict__ qg,
                                                   const bf16* __restrict__ kg_,
                                                   const bf16* __restrict__ vT,
                                                   bf16* __restrict__ cat) {
    __shared__ __align__(16) char lds[65536];
    char* Kl0 = lds;
    char* Kl1 = lds + 8192;
    char* Vl0 = lds + 16384;
    char* Vl1 = lds + 24576;

    int bidx = blockIdx.x;
    int bh = bidx & 31;
    int qblk = bidx >> 5;
    int b = bh >> 4, hh = bh & 15;
    int tid = threadIdx.x;
    int wv = tid >> 6, l = tid & 63;
    int h = l >> 5, ln = l & 31;
    int sw = (ln & 7) << 4;

    char* Pw = lds + 32768 + wv * 4096;

    const bf16* qbase = qg + ((long)bh * 2048 + qblk * 256 + wv * 32 + ln) * 64 + h * 8;
    bf16x8 qf[4];
#pragma unroll
    for (int ds = 0; ds < 4; ++ds) qf[ds] = *(const bf16x8*)(qbase + ds * 16);

    f32x16 Oa0 = {}, Oa1 = {};
    float m = -1e30f, lsum = 0.0f;

    int kr = tid >> 3, kg = tid & 7;
    int swb = (kg * 16) ^ ((kr & 7) << 4);
    const bf16* gK = kg_ + ((long)bh * 2048 + kr) * 64 + kg * 8;
    const bf16* gV = vT + ((long)bh * 64 + kr) * 2048 + kg * 8;

    bf16x8 rk = *(const bf16x8*)gK;
    bf16x8 rv = *(const bf16x8*)gV;
    *(bf16x8*)(Kl0 + kr * 128 + swb) = rk;
    *(bf16x8*)(Vl0 + kr * 128 + swb) = rv;
    __syncthreads();

    int c = 0;
    for (int t = 0; t < 32; ++t) {
        if (t < 31) {
            rk = *(const bf16x8*)(gK + (long)(t + 1) * 4096);
            rv = *(const bf16x8*)(gV + (t + 1) * 64);
        }
        const char* Kc = c ? Kl1 : Kl0;
        const char* Vc = c ? Vl1 : Vl0;

        f32x16 S0 = {}, S1 = {};
#pragma unroll
        for (int ds = 0; ds < 4; ++ds) {
            bf16x8 kf0 = *(const bf16x8*)(Kc + ln * 128 + ((ds * 32 + h * 16) ^ sw));
            bf16x8 kf1 = *(const bf16x8*)(Kc + (32 + ln) * 128 + ((ds * 32 + h * 16) ^ sw));
            S0 = __builtin_amdgcn_mfma_f32_32x32x16_bf16(kf0, qf[ds], S0, 0, 0, 0);
            S1 = __builtin_amdgcn_mfma_f32_32x32x16_bf16(kf1, qf[ds], S1, 0, 0, 0);
        }

        float tmax = S0[0];
#pragma unroll
        for (int r = 1; r < 16; ++r) tmax = fmaxf(tmax, S0[r]);
#pragma unroll
        for (int r = 0; r < 16; ++r) tmax = fmaxf(tmax, S1[r]);
        tmax = fmaxf(tmax, __shfl_xor(tmax, 32, 64));

        if (!__all(tmax - m <= 8.0f)) {
            float mn = fmaxf(m, tmax);
            float es = ex2(m - mn);
            lsum *= es;
            m = mn;
#pragma unroll
            for (int r = 0; r < 16; ++r) {
                int rowq = (r & 3) + 8 * (r >> 2) + 4 * h;
                float esr = __shfl(es, rowq, 64);
                Oa0[r] *= esr;
                Oa1[r] *= esr;
            }
        }

        float ps = 0.0f;
#pragma unroll
        for (int kvt = 0; kvt < 2; ++kvt) {
            float p[16];
#pragma unroll
            for (int r = 0; r < 16; ++r) {
                float v = ex2((kvt ? S1[r] : S0[r]) - m);
                p[r] = v;
                ps += v;
            }
#pragma unroll
            for (int i = 0; i < 8; ++i) {
                union { bf16 bb[2]; unsigned u; } pr;
                pr.bb[0] = (bf16)p[2 * i];
                pr.bb[1] = (bf16)p[2 * i + 1];
                int kv = ((2 * i) & 3) + 8 * (i >> 1) + 4 * h + 32 * kvt;
                *(unsigned*)(Pw + ln * 128 + ((kv * 2) ^ sw)) = pr.u;
            }
        }
        lsum += ps + __shfl_xor(ps, 32, 64);

        asm volatile("s_waitcnt lgkmcnt(0)" ::: "memory");

        bf16x8 pa[4];
#pragma unroll
        for (int s = 0; s < 4; ++s)
            pa[s] = *(const bf16x8*)(Pw + ln * 128 + ((s * 32 + h * 16) ^ sw));

#pragma unroll
        for (int s = 0; s < 4; ++s) {
            bf16x8 vf0 = *(const bf16x8*)(Vc + ln * 128 + ((s * 32 + h * 16) ^ sw));
            bf16x8 vf1 = *(const bf16x8*)(Vc + (32 + ln) * 128 + ((s * 32 + h * 16) ^ sw));
            Oa0 = __builtin_amdgcn_mfma_f32_32x32x16_bf16(pa[s], vf0, Oa0, 0, 0, 0);
            Oa1 = __builtin_amdgcn_mfma_f32_32x32x16_bf16(pa[s], vf1, Oa1, 0, 0, 0);
        }

        __syncthreads();
        if (t < 31) {
            char* Kn = c ? Kl0 : Kl1;
            char* Vn = c ? Vl0 : Vl1;
            *(bf16x8*)(Kn + kr * 128 + swb) = rk;
            *(bf16x8*)(Vn + kr * 128 + swb) = rv;
        }
        __syncthreads();
        c ^= 1;
    }

#pragma unroll
    for (int r = 0; r < 16; ++r) {
        int rowq = (r & 3) + 8 * (r >> 2) + 4 * h;
        float ls = __shfl(lsum, rowq, 64);
        float inv = 1.0f / ls;
        long trow = (long)b * 2048 + qblk * 256 + wv * 32 + rowq;
        cat[trow * 5120 + hh * 64 + ln] = (bf16)(Oa0[r] * inv);
        cat[trow * 5120 + hh * 64 + 32 + ln] = (bf16)(Oa1[r] * inv);
    }
}

// ---------------- launch ----------------

extern "C" void kernel_launch(void* const* d_in, const int* in_sizes, int n_in,
                              void* d_out, int out_size, void* d_ws, size_t ws_size,
                              hipStream_t stream) {
    const float* x  = (const float*)d_in[0];
    const float* pe = (const float*)d_in[1];
    const float* W1 = (const float*)d_in[2];
    const float* b1 = (const float*)d_in[3];
    const float* W2 = (const float*)d_in[4];
    const float* b2 = (const float*)d_in[5];
    const float* qs = (const float*)d_in[6];
    const float* ks = (const float*)d_in[7];
    float* out = (float*)d_out;

    char* ws = (char*)d_ws;
    bf16* xb  = (bf16*)(ws);                  // 4096*1024*2      =  8388608
    bf16* w1t = (bf16*)(ws + 8388608);        // 7168*1024*2      = 14680064
    bf16* w2t = (bf16*)(ws + 23068672);       // 1024*5120*2      = 10485760
    bf16* h   = (bf16*)(ws + 33554432);       // 4096*7168*2      = 58720256
    bf16* qb  = (bf16*)(ws + 92274688);       // 32*2048*64*2     =  8388608
    bf16* kb  = (bf16*)(ws + 100663296);      //                  =  8388608
    bf16* vT  = (bf16*)(ws + 109051904);      //                  =  8388608
    bf16* cat = (bf16*)(ws + 117440512);      // 4096*5120*2      = 41943040
    // split-K partials (4 x 4096 x 1024 f32 = 67108864 B) reuse h/qb region
    // (h and qb are dead by the time gemm256<1> runs).
    float* part = (float*)(ws + 33554432);

    f2b_kernel<<<4096, 256, 0, stream>>>(x, xb, 4194304L);
    transpose_f2b<<<dim3(224, 32), 256, 0, stream>>>(W1, w1t, 1024, 7168);
    transpose_f2b<<<dim3(32, 160), 256, 0, stream>>>(W2, w2t, 5120, 1024);

    // GEMM1 + bias + fused GELU (writes h cols<3072, cat cols>=3072)
    gemm256<0><<<dim3(448), 512, 0, stream>>>(xb, w1t, b1, h, cat, 4096, 7168, 1024, 1024);

    qkv_kernel<<<4096, 256, 0, stream>>>(h, pe, qs, ks, qb, kb);
    vtrans_kernel<<<dim3(32, 32), 256, 0, stream>>>(h, vT);

    attn_kernel<<<256, 512, 0, stream>>>(qb, kb, vT, cat);

    // GEMM2 split-K(4) partials + reduce
    gemm256<1><<<dim3(16, 4, 4), 512, 0, stream>>>(cat, w2t, nullptr, part, nullptr, 4096, 1024, 5120, 1280);
    reduce4_kernel<<<2048, 256, 0, stream>>>(part, b2, out);
}